// Round 14
// baseline (125.481 us; speedup 1.0000x reference)
//
#include <hip/hip_runtime.h>

typedef _Float16 f16;
typedef _Float16 f16x8 __attribute__((ext_vector_type(8)));
typedef __bf16 bf16x8 __attribute__((ext_vector_type(8)));
typedef float floatx4 __attribute__((ext_vector_type(4)));
typedef unsigned short u16;
typedef unsigned int u32;

#define B_N   8
#define T_SEQ 4096
#define DIM   64
#define NIT   32          // K-tiles of 128 (4 key-slices x 32 per wave)
#define FRAG  512         // fragment = 512 u16 (1 KB): lane holds row[ln], chunk qd*8..+8
#define XSTR  72
#define LOG2E 1.44269504f

#if __has_builtin(__builtin_amdgcn_exp2f)
#define EXP2(x) __builtin_amdgcn_exp2f(x)
#else
#define EXP2(x) exp2f(x)
#endif

// quad-transpose: C-layout chunks (k=ct*16+qd*4+r at col=ln) -> B-layout (k=qd*8+j, col=ln).
// p0 = 4 packed halves for ct=0, p1 = ct=1. Result: 8 packed halves, reg j = k qd*8+j.
__device__ __forceinline__ uint4 xpose(uint2 p0, uint2 p1, int qd, int ln) {
  const int pos = qd & 1;
  u32 mx = pos ? p1.x : p0.x, my = pos ? p1.y : p0.y;   // v[pos]
  u32 ox = pos ? p0.x : p1.x, oy = pos ? p0.y : p1.y;   // v[pos^1]
  u32 tx = (u32)__shfl_xor((int)ox, 16, 64);            // partner's v[pos]
  u32 ty = (u32)__shfl_xor((int)oy, 16, 64);
  u32 lox = pos ? tx : mx, loy = pos ? ty : my;         // chunk from even quad of pair
  u32 hix = pos ? mx : tx, hiy = pos ? my : ty;         // odd quad of pair
  const int src = ((2 * pos + (qd >> 1)) << 4) | ln;    // holder->target pull
  uint4 r;
  r.x = (u32)__shfl((int)lox, src, 64);
  r.y = (u32)__shfl((int)loy, src, 64);
  r.z = (u32)__shfl((int)hix, src, 64);
  r.w = (u32)__shfl((int)hiy, src, 64);
  return r;
}

__device__ __forceinline__ uint2 pack_bf4(floatx4 v) {
  __bf16 b0 = (__bf16)v[0], b1 = (__bf16)v[1], b2 = (__bf16)v[2], b3 = (__bf16)v[3];
  uint2 r;
  r.x = ((u32)__builtin_bit_cast(u16, b1) << 16) | __builtin_bit_cast(u16, b0);
  r.y = ((u32)__builtin_bit_cast(u16, b3) << 16) | __builtin_bit_cast(u16, b2);
  return r;
}
__device__ __forceinline__ uint2 pack_f16x4(floatx4 v, float sc) {
  f16 b0 = (f16)(v[0] * sc), b1 = (f16)(v[1] * sc), b2 = (f16)(v[2] * sc), b3 = (f16)(v[3] * sc);
  uint2 r;
  r.x = ((u32)__builtin_bit_cast(u16, b1) << 16) | __builtin_bit_cast(u16, b0);
  r.y = ((u32)__builtin_bit_cast(u16, b3) << 16) | __builtin_bit_cast(u16, b2);
  return r;
}

// ---- prep: Kswz (f16 X fragments) + Vswz (bf16 V^T fragments) only ----
__launch_bounds__(256, 2)
__global__ void prep_kernel(const float* __restrict__ X,
                            u16* __restrict__ Kswz, u16* __restrict__ Vswz) {
  __shared__ __attribute__((aligned(16))) u16 Xs[DIM * XSTR];
  const int tid = threadIdx.x;
  const int lane = tid & 63, w = tid >> 6, qd = lane >> 4, ln = lane & 15;
  const int b = blockIdx.y, tx = blockIdx.x;
  const long xbase = ((long)b * T_SEQ + tx * 64) * DIM;

  {
    const int r = tid >> 2, c0 = (tid & 3) * 16;
    float v[16];
#pragma unroll
    for (int i = 0; i < 4; i++)
      *(float4*)&v[i * 4] = *(const float4*)(X + xbase + (long)r * DIM + c0 + i * 4);
    u16 h[16];
#pragma unroll
    for (int j = 0; j < 16; j++) h[j] = __builtin_bit_cast(u16, (f16)v[j]);
    *(uint4*)&Xs[r * XSTR + c0] = *(uint4*)&h[0];
    *(uint4*)&Xs[r * XSTR + c0 + 8] = *(uint4*)&h[8];
  }
  __syncthreads();

  // K fragments (A-layout rows)
  {
    const long R = (long)b * (T_SEQ / 16) + tx * 4 + w;
#pragma unroll
    for (int ks = 0; ks < 2; ks++) {
      f16x8 kv = *(const f16x8*)&Xs[(w * 16 + ln) * XSTR + ks * 32 + qd * 8];
      *(f16x8*)(Kswz + (R * 2 + ks) * FRAG + lane * 8) = kv;
    }
  }
  // V^T fragments: wave w -> d-block Cb = b*4+w
  {
    const long Cb = (long)b * 4 + w;
#pragma unroll
    for (int J = 0; J < 2; J++) {
      bf16x8 vv;
#pragma unroll
      for (int j = 0; j < 8; j++) {
        f16 hv = __builtin_bit_cast(f16, Xs[(J * 32 + qd * 8 + j) * XSTR + w * 16 + ln]);
        vv[j] = (__bf16)(float)hv;
      }
      *(bf16x8*)(Vswz + (Cb * (T_SEQ / 32) + tx * 2 + J) * FRAG + lane * 8) = vv;
    }
  }
}

// ---- main: barrier-free K-loop; in-register P transpose; self-computed Q ----
__launch_bounds__(512, 4)
__global__ void attn_kernel(const u16* __restrict__ Kswz, const u16* __restrict__ Vswz,
                            const float* __restrict__ W, float* __restrict__ out) {
  __shared__ __attribute__((aligned(16))) float Opart[8][16][68];  // 34816 B
  __shared__ float lpart[8][32];                                    // 1024 B

  const int tid = threadIdx.x;
  const int lane = tid & 63, w = tid >> 6, qd = lane >> 4, ln = lane & 15;
  const int h = w >> 2;            // q-half (32 rows)
  const int s = w & 3;             // key-slice (32 keys of 128)
  const int bid = blockIdx.x;
  const int b = bid & 7;           // batch == XCD for L2 affinity
  const int q0 = (bid >> 3) * 64;
  const long bbase = (long)b * T_SEQ * DIM;
  const long RB = (long)b * (T_SEQ / 16);

  // ---- Q-GEMM (one-time): accT[e][q] = mfma(A=W^T gather, B=X frags) ----
  f16x8 bXq[2][2];
#pragma unroll
  for (int rb = 0; rb < 2; rb++)
#pragma unroll
    for (int ks = 0; ks < 2; ks++)
      bXq[rb][ks] = *(const f16x8*)(Kswz +
          ((RB + (q0 >> 4) + h * 2 + rb) * 2 + ks) * FRAG + lane * 8);

  floatx4 accT[4][2];
#pragma unroll
  for (int eb = 0; eb < 4; eb++)
#pragma unroll
    for (int rb = 0; rb < 2; rb++) accT[eb][rb] = (floatx4)0.0f;
#pragma unroll
  for (int ks = 0; ks < 2; ks++)
#pragma unroll
    for (int eb = 0; eb < 4; eb++) {
      f16 tw[8];
#pragma unroll
      for (int j = 0; j < 8; j++)
        tw[j] = (f16)W[(ks * 32 + qd * 8 + j) * DIM + eb * 16 + ln];
      f16x8 aW = *(const f16x8*)tw;
#pragma unroll
      for (int rb = 0; rb < 2; rb++)
        accT[eb][rb] = __builtin_amdgcn_mfma_f32_16x16x32_f16(aW, bXq[rb][ks], accT[eb][rb], 0, 0, 0);
    }

  // transpose accT -> bQ[rb][ks] (f16 B-layout, LOG2E folded)
  f16x8 bQ[2][2];
#pragma unroll
  for (int rb = 0; rb < 2; rb++)
#pragma unroll
    for (int ks = 0; ks < 2; ks++) {
      uint2 p0 = pack_f16x4(accT[ks * 2 + 0][rb], LOG2E);
      uint2 p1 = pack_f16x4(accT[ks * 2 + 1][rb], LOG2E);
      uint4 t = xpose(p0, p1, qd, ln);
      bQ[rb][ks] = __builtin_bit_cast(f16x8, t);
    }

  // ---- main loop: wave's 32 keys per iter, no barriers, no LDS ----
  floatx4 O[4][2];   // O^T[d = db*16 + qd*4+r][q = ln + h*32 + rb*16]
  float lacc[2] = {0.f, 0.f};
#pragma unroll
  for (int db = 0; db < 4; db++)
#pragma unroll
    for (int rb = 0; rb < 2; rb++) O[db][rb] = (floatx4)0.0f;

  const u16* pK = Kswz + (RB + s * 2) * 2 * FRAG + lane * 8;
  const u16* pV = Vswz + ((long)(b * 4) * (T_SEQ / 32) + s) * FRAG + lane * 8;

#pragma unroll 1
  for (int kt = 0; kt < NIT; kt++) {
    f16x8 kc[2][2];
#pragma unroll
    for (int ct = 0; ct < 2; ct++)
#pragma unroll
      for (int ks = 0; ks < 2; ks++)
        kc[ct][ks] = *(const f16x8*)(pK + (long)(kt * 16 + ct * 2 + ks) * FRAG);
    bf16x8 aV[4];
#pragma unroll
    for (int db = 0; db < 4; db++)
      aV[db] = *(const bf16x8*)(pV + ((long)db * (T_SEQ / 32) + kt * 4) * FRAG);

    // S^T = K Q^T : St[ct][rb], k = ct*16+qd*4+r, q = ln
    floatx4 St[2][2];
#pragma unroll
    for (int ct = 0; ct < 2; ct++)
#pragma unroll
      for (int rb = 0; rb < 2; rb++) St[ct][rb] = (floatx4)0.0f;
#pragma unroll
    for (int ks = 0; ks < 2; ks++)
#pragma unroll
      for (int ct = 0; ct < 2; ct++)
#pragma unroll
        for (int rb = 0; rb < 2; rb++)
          St[ct][rb] = __builtin_amdgcn_mfma_f32_16x16x32_f16(kc[ct][ks], bQ[rb][ks], St[ct][rb], 0, 0, 0);

    // P = 2^S' -> bf16 B-layout via in-register quad transpose
    bf16x8 bP[2];
#pragma unroll
    for (int rb = 0; rb < 2; rb++) {
      floatx4 e0, e1;
      float ps = 0.f;
#pragma unroll
      for (int r = 0; r < 4; r++) { e0[r] = EXP2(St[0][rb][r]); ps += e0[r]; }
#pragma unroll
      for (int r = 0; r < 4; r++) { e1[r] = EXP2(St[1][rb][r]); ps += e1[r]; }
      lacc[rb] += ps;
      bP[rb] = __builtin_bit_cast(bf16x8, xpose(pack_bf4(e0), pack_bf4(e1), qd, ln));
    }

    // O^T += V^T P^T
#pragma unroll
    for (int db = 0; db < 4; db++)
#pragma unroll
      for (int rb = 0; rb < 2; rb++)
        O[db][rb] = __builtin_amdgcn_mfma_f32_16x16x32_bf16(aV[db], bP[rb], O[db][rb], 0, 0, 0);
  }

  // l: per-lane covers 8 of the wave's 32 keys (its qd) -> reduce across quads
#pragma unroll
  for (int rb = 0; rb < 2; rb++) {
    float v = lacc[rb];
    v += __shfl_xor(v, 16, 64);
    v += __shfl_xor(v, 32, 64);
    if (qd == 0) lpart[w][rb * 16 + ln] = v;
  }

  // epilogue: reduce O over 4 key-slices per q-half; 2 rounds over rb
#pragma unroll 1
  for (int rb = 0; rb < 2; rb++) {
    __syncthreads();
#pragma unroll
    for (int db = 0; db < 4; db++)
      *(float4*)&Opart[w][ln][db * 16 + qd * 4] = __builtin_bit_cast(float4, O[db][rb]);
    __syncthreads();
    const int hh = tid >> 8;          // 0..1
    const int ql = (tid >> 4) & 15;   // 0..15
    const int d4 = tid & 15;          // 0..15 (float4 over d)
    float4 a = {0.f, 0.f, 0.f, 0.f};
    float l = 0.f;
#pragma unroll
    for (int ss = 0; ss < 4; ss++) {
      const int ww = hh * 4 + ss;
      float4 p = *(const float4*)&Opart[ww][ql][d4 * 4];
      a.x += p.x; a.y += p.y; a.z += p.z; a.w += p.w;
      l += lpart[ww][rb * 16 + ql];
    }
    float inv = 1.0f / l;
    float4 o;
    o.x = a.x * inv; o.y = a.y * inv; o.z = a.z * inv; o.w = a.w * inv;
    *(float4*)(out + bbase + (long)(q0 + hh * 32 + rb * 16 + ql) * DIM + d4 * 4) = o;
  }
}

extern "C" void kernel_launch(void* const* d_in, const int* in_sizes, int n_in,
                              void* d_out, int out_size, void* d_ws, size_t ws_size,
                              hipStream_t stream) {
  const float* X = (const float*)d_in[0];
  const float* W = (const float*)d_in[1];
  float* out = (float*)d_out;
  const size_t SZ = (size_t)B_N * T_SEQ * DIM * 2;  // 4 MB per u16 array
  u16* Kswz = (u16*)d_ws;
  u16* Vswz = (u16*)((char*)d_ws + SZ);
  prep_kernel<<<dim3(T_SEQ / 64, B_N), 256, 0, stream>>>(X, Kswz, Vswz);
  attn_kernel<<<dim3(B_N * (T_SEQ / 64)), 512, 0, stream>>>(Kswz, Vswz, W, out);
}

// Round 15
// 124.478 us; speedup vs baseline: 1.0081x; 1.0081x over previous
//
#include <hip/hip_runtime.h>

typedef _Float16 f16;
typedef _Float16 f16x8 __attribute__((ext_vector_type(8)));
typedef __bf16 bf16x8 __attribute__((ext_vector_type(8)));
typedef float floatx4 __attribute__((ext_vector_type(4)));
typedef unsigned short u16;
typedef unsigned int u32;

#define B_N   8
#define T_SEQ 4096
#define DIM   64
#define NIT   32          // K-tiles of 128 (4 key-slices x 32 keys per wave)
#define FRAG  512         // fragment = 512 u16 (1 KB)
#define PSTR  40          // P row stride in u16 (80 B, 16B-aligned)
#define LOG2E 1.44269504f

#if __has_builtin(__builtin_amdgcn_exp2f)
#define EXP2(x) __builtin_amdgcn_exp2f(x)
#else
#define EXP2(x) exp2f(x)
#endif

// quad-transpose (one-time, Q only): C-layout (k=ct*16+qd*4+r, col=ln) -> B-layout (k=qd*8+j)
__device__ __forceinline__ uint4 xpose(uint2 p0, uint2 p1, int qd, int ln) {
  const int pos = qd & 1;
  u32 mx = pos ? p1.x : p0.x, my = pos ? p1.y : p0.y;
  u32 ox = pos ? p0.x : p1.x, oy = pos ? p0.y : p1.y;
  u32 tx = (u32)__shfl_xor((int)ox, 16, 64);
  u32 ty = (u32)__shfl_xor((int)oy, 16, 64);
  u32 lox = pos ? tx : mx, loy = pos ? ty : my;
  u32 hix = pos ? mx : tx, hiy = pos ? my : ty;
  const int src = ((2 * pos + (qd >> 1)) << 4) | ln;
  uint4 r;
  r.x = (u32)__shfl((int)lox, src, 64);
  r.y = (u32)__shfl((int)loy, src, 64);
  r.z = (u32)__shfl((int)hix, src, 64);
  r.w = (u32)__shfl((int)hiy, src, 64);
  return r;
}
__device__ __forceinline__ uint2 pack_bf4(floatx4 v) {
  __bf16 b0 = (__bf16)v[0], b1 = (__bf16)v[1], b2 = (__bf16)v[2], b3 = (__bf16)v[3];
  uint2 r;
  r.x = ((u32)__builtin_bit_cast(u16, b1) << 16) | __builtin_bit_cast(u16, b0);
  r.y = ((u32)__builtin_bit_cast(u16, b3) << 16) | __builtin_bit_cast(u16, b2);
  return r;
}
__device__ __forceinline__ uint2 pack_f16x4(floatx4 v, float sc) {
  f16 b0 = (f16)(v[0] * sc), b1 = (f16)(v[1] * sc), b2 = (f16)(v[2] * sc), b3 = (f16)(v[3] * sc);
  uint2 r;
  r.x = ((u32)__builtin_bit_cast(u16, b1) << 16) | __builtin_bit_cast(u16, b0);
  r.y = ((u32)__builtin_bit_cast(u16, b3) << 16) | __builtin_bit_cast(u16, b2);
  return r;
}

// ---- prep: LDS-free, barrier-free. Kswz = f16 X fragments; Vswz = bf16 V^T fragments ----
__launch_bounds__(256, 4)
__global__ void prep_kernel(const float* __restrict__ X,
                            u16* __restrict__ Kswz, u16* __restrict__ Vswz) {
  const int tid = threadIdx.x;
  const int lane = tid & 63, w = tid >> 6, qd = lane >> 4, ln = lane & 15;
  const int b = blockIdx.y, tx = blockIdx.x;
  const long xbase = ((long)b * T_SEQ + tx * 64) * DIM;

  // K fragments: wave w -> row-block tx*4 + w; lane loads its own 8-float chunks
  {
    const long R = (long)b * (T_SEQ / 16) + tx * 4 + w;
    const float* src = X + xbase + (long)(w * 16 + ln) * DIM + qd * 8;
#pragma unroll
    for (int ks = 0; ks < 2; ks++) {
      float4 a = *(const float4*)(src + ks * 32);
      float4 c = *(const float4*)(src + ks * 32 + 4);
      f16 h[8] = {(f16)a.x, (f16)a.y, (f16)a.z, (f16)a.w,
                  (f16)c.x, (f16)c.y, (f16)c.z, (f16)c.w};
      *(f16x8*)(Kswz + (R * 2 + ks) * FRAG + lane * 8) = *(const f16x8*)h;
    }
  }
  // V^T fragments: wave w -> d-block b*4+w; gather X[t][d] column chunks
  {
    const long Cb = (long)b * 4 + w;
#pragma unroll
    for (int J = 0; J < 2; J++) {
      bf16x8 vv;
#pragma unroll
      for (int j = 0; j < 8; j++) {
        float x = X[xbase + (long)(J * 32 + qd * 8 + j) * DIM + w * 16 + ln];
        vv[j] = (__bf16)x;
      }
      *(bf16x8*)(Vswz + (Cb * (T_SEQ / 32) + tx * 2 + J) * FRAG + lane * 8) = vv;
    }
  }
}

// ---- main: 8-wave blocks; wave-private P (no barriers in loop); self-computed Q ----
__launch_bounds__(512, 4)
__global__ void attn_kernel(const u16* __restrict__ Kswz, const u16* __restrict__ Vswz,
                            const float* __restrict__ W, float* __restrict__ out) {
  __shared__ __attribute__((aligned(16))) char smem[8 * 16 * 68 * 4];  // 34816 B: Ps | Opart
  __shared__ float lpart[8][32];

  u16* Ps = (u16*)smem;           // 8 waves x 32 rows x PSTR u16 = 20480 B
  float* Opart = (float*)smem;

  const int tid = threadIdx.x;
  const int lane = tid & 63, w = tid >> 6, qd = lane >> 4, ln = lane & 15;
  const int h = w >> 2;            // q-half (32 rows)
  const int s = w & 3;             // key-slice (32 of 128 keys/iter)
  const int bid = blockIdx.x;
  const int b = bid & 7;           // batch == XCD for L2 affinity
  const int q0 = (bid >> 3) * 64;
  const long bbase = (long)b * T_SEQ * DIM;
  const long RB = (long)b * (T_SEQ / 16);
  u16* Pw = Ps + w * (32 * PSTR);

  // ---- Q-GEMM (one-time): accT[e][q] = W^T(A) x X(B) ----
  f16x8 bXq[2][2];
#pragma unroll
  for (int rb = 0; rb < 2; rb++)
#pragma unroll
    for (int ks = 0; ks < 2; ks++)
      bXq[rb][ks] = *(const f16x8*)(Kswz +
          ((RB + (q0 >> 4) + h * 2 + rb) * 2 + ks) * FRAG + lane * 8);

  floatx4 accT[4][2];
#pragma unroll
  for (int eb = 0; eb < 4; eb++)
#pragma unroll
    for (int rb = 0; rb < 2; rb++) accT[eb][rb] = (floatx4)0.0f;
#pragma unroll
  for (int ks = 0; ks < 2; ks++)
#pragma unroll
    for (int eb = 0; eb < 4; eb++) {
      f16 tw[8];
#pragma unroll
      for (int j = 0; j < 8; j++)
        tw[j] = (f16)W[(ks * 32 + qd * 8 + j) * DIM + eb * 16 + ln];
      f16x8 aW = *(const f16x8*)tw;
#pragma unroll
      for (int rb = 0; rb < 2; rb++)
        accT[eb][rb] = __builtin_amdgcn_mfma_f32_16x16x32_f16(aW, bXq[rb][ks], accT[eb][rb], 0, 0, 0);
    }

  f16x8 bQ[2][2];   // B-layout Q (k=e), LOG2E folded
#pragma unroll
  for (int rb = 0; rb < 2; rb++)
#pragma unroll
    for (int ks = 0; ks < 2; ks++) {
      uint2 p0 = pack_f16x4(accT[ks * 2 + 0][rb], LOG2E);
      uint2 p1 = pack_f16x4(accT[ks * 2 + 1][rb], LOG2E);
      bQ[rb][ks] = __builtin_bit_cast(f16x8, xpose(p0, p1, qd, ln));
    }

  // ---- K-loop: no barriers, wave-private P round-trip ----
  floatx4 O[2][4];
  float lacc[2] = {0.f, 0.f};
#pragma unroll
  for (int rb = 0; rb < 2; rb++)
#pragma unroll
    for (int cd = 0; cd < 4; cd++) O[rb][cd] = (floatx4)0.0f;

  const u16* pK = Kswz + (RB + s * 2) * 2 * FRAG + lane * 8;
  const u16* pV = Vswz + ((long)b * 4 * (T_SEQ / 32) + s) * FRAG + lane * 8;

#pragma unroll 1
  for (int kt = 0; kt < NIT; kt++) {
    f16x8 kc[2][2];
#pragma unroll
    for (int ct = 0; ct < 2; ct++)
#pragma unroll
      for (int ks = 0; ks < 2; ks++)
        kc[ct][ks] = *(const f16x8*)(pK + (long)(kt * 16 + ct * 2 + ks) * FRAG);
    bf16x8 bV[4];
#pragma unroll
    for (int cd = 0; cd < 4; cd++)
      bV[cd] = *(const bf16x8*)(pV + ((long)cd * (T_SEQ / 32) + kt * 4) * FRAG);

    // S^T: St[ct][rb], k = ct*16+qd*4+r, q = rb*16+ln
    floatx4 St[2][2];
#pragma unroll
    for (int ct = 0; ct < 2; ct++)
#pragma unroll
      for (int rb = 0; rb < 2; rb++) St[ct][rb] = (floatx4)0.0f;
#pragma unroll
    for (int ks = 0; ks < 2; ks++)
#pragma unroll
      for (int ct = 0; ct < 2; ct++)
#pragma unroll
        for (int rb = 0; rb < 2; rb++)
          St[ct][rb] = __builtin_amdgcn_mfma_f32_16x16x32_f16(kc[ct][ks], bQ[rb][ks], St[ct][rb], 0, 0, 0);

    // P = 2^S'; per-lane l (q=rb*16+ln); b64 writes to wave-private LDS
#pragma unroll
    for (int rb = 0; rb < 2; rb++)
#pragma unroll
      for (int ct = 0; ct < 2; ct++) {
        floatx4 e;
        float ps = 0.f;
#pragma unroll
        for (int r = 0; r < 4; r++) { e[r] = EXP2(St[ct][rb][r]); ps += e[r]; }
        lacc[rb] += ps;
        *(uint2*)&Pw[(rb * 16 + ln) * PSTR + ct * 16 + qd * 4] = pack_bf4(e);
      }

    // O += P V (aP read = A-layout b128 from own P rows)
#pragma unroll
    for (int rb = 0; rb < 2; rb++) {
      bf16x8 aP = *(const bf16x8*)&Pw[(rb * 16 + ln) * PSTR + qd * 8];
#pragma unroll
      for (int cd = 0; cd < 4; cd++)
        O[rb][cd] = __builtin_amdgcn_mfma_f32_16x16x32_bf16(aP, bV[cd], O[rb][cd], 0, 0, 0);
    }
  }

  // l: reduce across quads (per-lane q = rb*16+ln)
#pragma unroll
  for (int rb = 0; rb < 2; rb++) {
    float v = lacc[rb];
    v += __shfl_xor(v, 16, 64);
    v += __shfl_xor(v, 32, 64);
    if (qd == 0) lpart[w][rb * 16 + ln] = v;
  }

  // epilogue: reduce O over 4 key-slices per q-half; 2 rounds over rb
#pragma unroll 1
  for (int rb = 0; rb < 2; rb++) {
    __syncthreads();  // round 0: loop P reads done + lpart published
#pragma unroll
    for (int cd = 0; cd < 4; cd++)
#pragma unroll
      for (int r = 0; r < 4; r++)
        Opart[w * 16 * 68 + (qd * 4 + r) * 68 + cd * 16 + ln] = O[rb][cd][r];
    __syncthreads();
    const int hh = tid >> 8;          // 0..1 q-half
    const int ql = (tid >> 4) & 15;   // 0..15 row within 16
    const int d4 = tid & 15;          // float4 index over d
    float4 a = {0.f, 0.f, 0.f, 0.f};
    float l = 0.f;
#pragma unroll
    for (int ss = 0; ss < 4; ss++) {
      const int ww = hh * 4 + ss;
      float4 p = *(const float4*)&Opart[ww * 16 * 68 + ql * 68 + d4 * 4];
      a.x += p.x; a.y += p.y; a.z += p.z; a.w += p.w;
      l += lpart[ww][rb * 16 + ql];
    }
    float inv = 1.0f / l;
    float4 o;
    o.x = a.x * inv; o.y = a.y * inv; o.z = a.z * inv; o.w = a.w * inv;
    *(float4*)(out + bbase + (long)(q0 + hh * 32 + rb * 16 + ql) * DIM + d4 * 4) = o;
  }
}

extern "C" void kernel_launch(void* const* d_in, const int* in_sizes, int n_in,
                              void* d_out, int out_size, void* d_ws, size_t ws_size,
                              hipStream_t stream) {
  const float* X = (const float*)d_in[0];
  const float* W = (const float*)d_in[1];
  float* out = (float*)d_out;
  const size_t SZ = (size_t)B_N * T_SEQ * DIM * 2;  // 4 MB per u16 array
  u16* Kswz = (u16*)d_ws;
  u16* Vswz = (u16*)((char*)d_ws + SZ);
  prep_kernel<<<dim3(T_SEQ / 64, B_N), 256, 0, stream>>>(X, Kswz, Vswz);
  attn_kernel<<<dim3(B_N * (T_SEQ / 64)), 512, 0, stream>>>(Kswz, Vswz, W, out);
}